// Round 3
// baseline (81.165 us; speedup 1.0000x reference)
//
#include <hip/hip_runtime.h>

#define VOCAB 100000
#define D     300
#define B     256
#define L     1000
#define H     512
#define C     5

#define SPLIT 10
#define CHUNK (L / SPLIT)   // 100 rows per gather block
#define D4    (D / 4)       // 75 float4 per row

// ws layout (floats)
#define WS_PARTIAL 0        // B*SPLIT*D = 768000 floats

// ---------------------------------------------------------------------------
// Kernel 1: gather + partial sum (~14 us, near L3-BW floor).
// grid = (B, SPLIT), block = 320 = 4 row-groups x 80 lanes, float4 loads.
// ---------------------------------------------------------------------------
__global__ __launch_bounds__(320) void gather_sum_kernel(
    const float* __restrict__ emb, const int* __restrict__ docs,
    float* __restrict__ partial) {
  const int b = blockIdx.x;
  const int s = blockIdx.y;
  const int t = threadIdx.x;
  const int rg = t / 80;
  const int lane = t - rg * 80;

  __shared__ int sidx[CHUNK];
  if (t < CHUNK) sidx[t] = docs[b * L + s * CHUNK + t];
  __syncthreads();

  float ax = 0.f, ay = 0.f, az = 0.f, aw = 0.f;
  if (lane < D4) {
#pragma unroll 5
    for (int l = 0; l < CHUNK; l += 4) {
      const int idx = sidx[l + rg];
      const float4 v =
          reinterpret_cast<const float4*>(emb + (size_t)idx * D)[lane];
      ax += v.x; ay += v.y; az += v.z; aw += v.w;
    }
  }

  __shared__ float4 sred[3][D4];
  if (rg > 0 && lane < D4) sred[rg - 1][lane] = make_float4(ax, ay, az, aw);
  __syncthreads();
  if (rg == 0 && lane < D4) {
#pragma unroll
    for (int g = 0; g < 3; ++g) {
      const float4 v = sred[g][lane];
      ax += v.x; ay += v.y; az += v.z; aw += v.w;
    }
    reinterpret_cast<float4*>(partial + (size_t)(b * SPLIT + s) * D)[lane] =
        make_float4(ax, ay, az, aw);
  }
}

// ---------------------------------------------------------------------------
// Kernel 2: fused MLP. grid = B/2 = 128 blocks, block = 1024 threads.
// Thread = (cg 0..127: 4 consecutive output cols, r 0..1: batch row,
//           ks 0..3: K-slice). Weights loaded as float4 along the column
//   axis -> 4 FMA per 16B coalesced load; K-slices combined through LDS.
// ---------------------------------------------------------------------------
__global__ __launch_bounds__(1024) void mlp_fused_kernel(
    const float* __restrict__ partial, const int* __restrict__ dlen,
    const float* __restrict__ W1, const float* __restrict__ b1,
    const float* __restrict__ W2, const float* __restrict__ b2,
    const float* __restrict__ W3, const float* __restrict__ b3,
    float* __restrict__ out) {
  const int bt = blockIdx.x;            // batch pair
  const int t = threadIdx.x;
  const int cg = t & 127;               // column group (4 cols)
  const int r = (t >> 7) & 1;           // batch row within pair
  const int ks = t >> 8;                // K-slice 0..3

  __shared__ float s_in[2][D];          // averaged inputs
  __shared__ float s_h1[2][H];
  __shared__ float s_h2[2][H];
  __shared__ float s_comb[4][2][H];     // K-slice partials

  // ---- Stage avg = (sum of partials) / len ----
  if (t < 2 * D) {
    const int rr = t < D ? 0 : 1;
    const int d = t - rr * D;
    const int b = bt * 2 + rr;
    const float* p = partial + (size_t)b * (SPLIT * D) + d;
    float s = 0.f;
#pragma unroll
    for (int k = 0; k < SPLIT; ++k) s += p[k * D];
    s_in[rr][d] = s / (float)dlen[b];
  }
  __syncthreads();

  // ---- Layer 1: K = 300, slice = 75 ----
  {
    float ax = 0.f, ay = 0.f, az = 0.f, aw = 0.f;
    const int k0 = ks * (D / 4);
#pragma unroll 15
    for (int k = k0; k < k0 + D / 4; ++k) {
      const float4 w = *reinterpret_cast<const float4*>(&W1[k * H + 4 * cg]);
      const float x = s_in[r][k];
      ax += x * w.x; ay += x * w.y; az += x * w.z; aw += x * w.w;
    }
    *reinterpret_cast<float4*>(&s_comb[ks][r][4 * cg]) =
        make_float4(ax, ay, az, aw);
  }
  __syncthreads();
  {
    const int rr = t >> 9;              // 0..1
    const int col = t & (H - 1);
    const float v = s_comb[0][rr][col] + s_comb[1][rr][col] +
                    s_comb[2][rr][col] + s_comb[3][rr][col] + b1[col];
    s_h1[rr][col] = fmaxf(v, 0.f);
  }
  __syncthreads();

  // ---- Layer 2: K = 512, slice = 128 ----
  {
    float ax = 0.f, ay = 0.f, az = 0.f, aw = 0.f;
    const int k0 = ks * (H / 4);
#pragma unroll 16
    for (int k = k0; k < k0 + H / 4; ++k) {
      const float4 w = *reinterpret_cast<const float4*>(&W2[k * H + 4 * cg]);
      const float x = s_h1[r][k];
      ax += x * w.x; ay += x * w.y; az += x * w.z; aw += x * w.w;
    }
    *reinterpret_cast<float4*>(&s_comb[ks][r][4 * cg]) =
        make_float4(ax, ay, az, aw);
  }
  __syncthreads();
  {
    const int rr = t >> 9;
    const int col = t & (H - 1);
    const float v = s_comb[0][rr][col] + s_comb[1][rr][col] +
                    s_comb[2][rr][col] + s_comb[3][rr][col] + b2[col];
    s_h2[rr][col] = fmaxf(v, 0.f);
  }
  __syncthreads();

  // ---- Head: 2 rows x 5 classes = 10 outputs, one wave each ----
  const int wv = t >> 6;
  const int ln = t & 63;
  if (wv < 2 * C) {
    const int rr = wv / C;
    const int c = wv - rr * C;
    float a = 0.f;
#pragma unroll
    for (int i = 0; i < H / 64; ++i) {
      const int h = i * 64 + ln;
      a += s_h2[rr][h] * W3[h * C + c];
    }
#pragma unroll
    for (int off = 32; off > 0; off >>= 1) a += __shfl_down(a, off);
    if (ln == 0) out[(bt * 2 + rr) * C + c] = a + b3[c];
  }
}

// ---------------------------------------------------------------------------
extern "C" void kernel_launch(void* const* d_in, const int* in_sizes, int n_in,
                              void* d_out, int out_size, void* d_ws,
                              size_t ws_size, hipStream_t stream) {
  const float* emb  = (const float*)d_in[0];
  const float* W1   = (const float*)d_in[1];
  const float* b1   = (const float*)d_in[2];
  const float* W2   = (const float*)d_in[3];
  const float* b2   = (const float*)d_in[4];
  const float* W3   = (const float*)d_in[5];
  const float* b3   = (const float*)d_in[6];
  const int*   docs = (const int*)d_in[7];
  const int*   dlen = (const int*)d_in[8];
  float* out = (float*)d_out;
  float* partial = (float*)d_ws + WS_PARTIAL;

  dim3 g1(B, SPLIT);
  gather_sum_kernel<<<g1, 320, 0, stream>>>(emb, docs, partial);
  mlp_fused_kernel<<<B / 2, 1024, 0, stream>>>(partial, dlen, W1, b1, W2, b2,
                                               W3, b3, out);
}

// Round 4
// 65.825 us; speedup vs baseline: 1.2330x; 1.2330x over previous
//
#include <hip/hip_runtime.h>

#define VOCAB 100000
#define D     300
#define B     256
#define L     1000
#define H     512
#define C     5

#define D4    (D / 4)      // 75 float4 per embedding row
#define NG    8            // row groups per block
#define GL    80           // lanes per row group (75 active)
#define RPG   (L / NG)     // 125 rows per group
#define NT    (NG * GL)    // 640 threads
#define KS1   (D / 4)      // 75: layer-1 K-slice
#define KS2   (H / 4)      // 128: layer-2 K-slice

// ---------------------------------------------------------------------------
// ONE kernel: per-block (per-document) gather-sum -> mean -> 3-layer MLP.
// grid = B = 256 blocks (1/CU), block = 640 threads (10 waves).
// No inter-kernel barriers: a block entering its MLP phase overlaps other
// blocks' gather phase, hiding weight-load latency structurally.
// ---------------------------------------------------------------------------
__global__ __launch_bounds__(NT) void dan_fused_kernel(
    const float* __restrict__ emb, const int* __restrict__ docs,
    const int* __restrict__ dlen,
    const float* __restrict__ W1, const float* __restrict__ b1,
    const float* __restrict__ W2, const float* __restrict__ b2,
    const float* __restrict__ W3, const float* __restrict__ b3,
    float* __restrict__ out) {
  const int b = blockIdx.x;
  const int t = threadIdx.x;

  __shared__ int    sidx[L];          // 4000 B
  __shared__ float4 sred[NG][D4];     // 9600 B
  __shared__ float4 s_in4[D4];        // 1200 B (viewed as float[D])
  __shared__ float  s_h1[H];          // 2048 B
  __shared__ float  s_h2[H];          // 2048 B
  __shared__ float  s_comb[4][H];     // 8192 B
  __shared__ float  s_len;

  for (int i = t; i < L; i += NT) sidx[i] = docs[b * L + i];
  if (t == 0) s_len = (float)dlen[b];
  __syncthreads();

  // ---- Gather + sum: group g sums rows [g*RPG, (g+1)*RPG) ----
  const int g = t / GL;
  const int lane = t - g * GL;
  if (lane < D4) {
    float ax = 0.f, ay = 0.f, az = 0.f, aw = 0.f;
    const int base = g * RPG;
#pragma unroll 5
    for (int i = 0; i < RPG; ++i) {
      const int idx = sidx[base + i];
      const float4 v =
          reinterpret_cast<const float4*>(emb + (size_t)idx * D)[lane];
      ax += v.x; ay += v.y; az += v.z; aw += v.w;
    }
    sred[g][lane] = make_float4(ax, ay, az, aw);
  }
  __syncthreads();

  // ---- Reduce 8 groups, divide by len ----
  if (t < D4) {
    float ax = 0.f, ay = 0.f, az = 0.f, aw = 0.f;
#pragma unroll
    for (int gg = 0; gg < NG; ++gg) {
      const float4 v = sred[gg][t];
      ax += v.x; ay += v.y; az += v.z; aw += v.w;
    }
    const float inv = 1.f / s_len;
    s_in4[t] = make_float4(ax * inv, ay * inv, az * inv, aw * inv);
  }
  __syncthreads();

  const float* s_in = reinterpret_cast<const float*>(s_in4);
  const int cg = t & 127;             // column group: 4 consecutive cols
  const int ks = (t >> 7) & 3;        // K-slice

  // ---- Layer 1: h1 = relu(avg @ W1 + b1), K=300 split 4x75 ----
  if (t < 512) {
    float ax = 0.f, ay = 0.f, az = 0.f, aw = 0.f;
    const int k0 = ks * KS1;
#pragma unroll 15
    for (int k = k0; k < k0 + KS1; ++k) {
      const float4 w = *reinterpret_cast<const float4*>(&W1[k * H + 4 * cg]);
      const float x = s_in[k];
      ax += x * w.x; ay += x * w.y; az += x * w.z; aw += x * w.w;
    }
    *reinterpret_cast<float4*>(&s_comb[ks][4 * cg]) =
        make_float4(ax, ay, az, aw);
  }
  __syncthreads();
  if (t < H) {
    const float v =
        s_comb[0][t] + s_comb[1][t] + s_comb[2][t] + s_comb[3][t] + b1[t];
    s_h1[t] = fmaxf(v, 0.f);
  }
  __syncthreads();

  // ---- Layer 2: h2 = relu(h1 @ W2 + b2), K=512 split 4x128 ----
  if (t < 512) {
    float ax = 0.f, ay = 0.f, az = 0.f, aw = 0.f;
    const int k0 = ks * KS2;
#pragma unroll 16
    for (int k = k0; k < k0 + KS2; ++k) {
      const float4 w = *reinterpret_cast<const float4*>(&W2[k * H + 4 * cg]);
      const float x = s_h1[k];
      ax += x * w.x; ay += x * w.y; az += x * w.z; aw += x * w.w;
    }
    *reinterpret_cast<float4*>(&s_comb[ks][4 * cg]) =
        make_float4(ax, ay, az, aw);
  }
  __syncthreads();
  if (t < H) {
    const float v =
        s_comb[0][t] + s_comb[1][t] + s_comb[2][t] + s_comb[3][t] + b2[t];
    s_h2[t] = fmaxf(v, 0.f);
  }
  __syncthreads();

  // ---- Head: out = h2 @ W3 + b3; wave w (<C) computes class w ----
  const int wv = t >> 6;
  const int ln = t & 63;
  if (wv < C) {
    float a = 0.f;
#pragma unroll
    for (int i = 0; i < H / 64; ++i) {
      const int h = i * 64 + ln;
      a += s_h2[h] * W3[h * C + wv];
    }
#pragma unroll
    for (int off = 32; off > 0; off >>= 1) a += __shfl_down(a, off);
    if (ln == 0) out[b * C + wv] = a + b3[wv];
  }
}

// ---------------------------------------------------------------------------
extern "C" void kernel_launch(void* const* d_in, const int* in_sizes, int n_in,
                              void* d_out, int out_size, void* d_ws,
                              size_t ws_size, hipStream_t stream) {
  const float* emb  = (const float*)d_in[0];
  const float* W1   = (const float*)d_in[1];
  const float* b1   = (const float*)d_in[2];
  const float* W2   = (const float*)d_in[3];
  const float* b2   = (const float*)d_in[4];
  const float* W3   = (const float*)d_in[5];
  const float* b3   = (const float*)d_in[6];
  const int*   docs = (const int*)d_in[7];
  const int*   dlen = (const int*)d_in[8];
  float* out = (float*)d_out;

  dan_fused_kernel<<<B, NT, 0, stream>>>(emb, docs, dlen, W1, b1, W2, b2, W3,
                                         b3, out);
}